// Round 10
// baseline (259.198 us; speedup 1.0000x reference)
//
#include <hip/hip_runtime.h>
#include <stdint.h>

#define NA 9
#define HH 50
#define WW 50
#define NPROP (HH*WW*NA)      // 22500
#define PRE_NMS 4000
#define POST_NMS 300
#define NWORDS 63             // ceil(4000/64) suppression words per row
#define ROWSTRIDE 64          // mask row stride in u64 words
#define MROWS 4032            // padded rows per image (63 windows * 64)
#define SELN 8192             // compaction capacity (top-4000 + threshold-bucket slack)
#define NMS_T 0.7f
#define FSTRIDE 16.0f

typedef unsigned long long ull;

__device__ __forceinline__ uint32_t f32_ord(float s) {
    uint32_t u = __float_as_uint(s);
    return (u & 0x80000000u) ? ~u : (u | 0x80000000u);
}

// ---------------------------------------------------------------------------
// Kernel 1: decode boxes + build keys + histogram of top-16 key bits.
// ---------------------------------------------------------------------------
__global__ void decode_hist(const float* __restrict__ scores,
                            const float* __restrict__ deltas,
                            const float* __restrict__ im_info,
                            const float* __restrict__ anchors,
                            ull* __restrict__ keys,
                            float4* __restrict__ boxes4,
                            uint32_t* __restrict__ hist, int B) {
    int t = blockIdx.x * blockDim.x + threadIdx.x;
    if (t >= B * NPROP) return;
    int b = t / NPROP;
    int i = t % NPROP;

    int a   = i % NA;
    int pos = i / NA;          // h*W + w
    int w   = pos % WW;
    int h   = pos / WW;

    float score = scores[((size_t)b*2*NA + NA + a)*(HH*WW) + pos];
    ull key = ((ull)f32_ord(score) << 32) | (ull)(0xFFFFFFFFu - (uint32_t)i);
    keys[t] = key;
    atomicAdd(&hist[((uint32_t)b << 16) | (uint32_t)(key >> 48)], 1u);

    float ax1 = anchors[a*4+0], ay1 = anchors[a*4+1];
    float ax2 = anchors[a*4+2], ay2 = anchors[a*4+3];
    float sx = (float)w * FSTRIDE, sy = (float)h * FSTRIDE;
    float x1 = ax1 + sx, y1 = ay1 + sy, x2 = ax2 + sx, y2 = ay2 + sy;
    float bw = x2 - x1 + 1.0f;
    float bh = y2 - y1 + 1.0f;
    float cx = x1 + 0.5f * bw;
    float cy = y1 + 0.5f * bh;

    const float* dp = deltas + (size_t)b*4*NA*(HH*WW);
    float dx = dp[(4*a+0)*(HH*WW)+pos];
    float dy = dp[(4*a+1)*(HH*WW)+pos];
    float dw = dp[(4*a+2)*(HH*WW)+pos];
    float dh = dp[(4*a+3)*(HH*WW)+pos];

    float pcx = dx * bw + cx;
    float pcy = dy * bh + cy;
    float pw  = expf(dw) * bw;
    float ph  = expf(dh) * bh;

    float wmax = im_info[b*3+1] - 1.0f;
    float hmax = im_info[b*3+0] - 1.0f;
    float px1 = fminf(fmaxf(pcx - 0.5f*pw, 0.0f), wmax);
    float py1 = fminf(fmaxf(pcy - 0.5f*ph, 0.0f), hmax);
    float px2 = fminf(fmaxf(pcx + 0.5f*pw, 0.0f), wmax);
    float py2 = fminf(fmaxf(pcy + 0.5f*ph, 0.0f), hmax);

    boxes4[t] = make_float4(px1, py1, px2, py2);
}

// ---------------------------------------------------------------------------
// Kernel 2: one block per image. Find the 16-bit threshold bucket from the
// histogram, compact all keys in buckets >= threshold to global ckeys.
// ---------------------------------------------------------------------------
__global__ __launch_bounds__(1024) void compact_kernel(
        const ull* __restrict__ keys,
        const uint32_t* __restrict__ hist,
        ull* __restrict__ ckeys,
        int* __restrict__ mcount) {
    __shared__ int sA[1024], sB[1024]; // coarse sums + scan ping-pong
    __shared__ int nfine[64];
    __shared__ int sSeg, aboveC, thr, lcount;
    int img = blockIdx.x, tid = threadIdx.x;
    const uint32_t* h = hist + ((uint32_t)img << 16);

    // --- Phase A: coarse per-64-bucket sums (vectorized uint4 loads) ---
    {
        const uint4* h4 = (const uint4*)h;
        uint32_t s = 0;
        #pragma unroll
        for (int u = 0; u < 16; ++u) {
            uint4 v = h4[(tid << 4) | u];
            s += v.x + v.y + v.z + v.w;
        }
        sA[tid] = (int)s;
    }
    __syncthreads();
    // cumulative-from-top: cft[t] = sum_{u>=t} coarse[u]
    int* curp = sA; int* nxtp = sB;
    for (int d = 1; d < 1024; d <<= 1) {
        int v = curp[tid] + ((tid + d < 1024) ? curp[tid + d] : 0);
        nxtp[tid] = v;
        __syncthreads();
        int* tmp = curp; curp = nxtp; nxtp = tmp;
    }
    {
        int cftS  = curp[tid];
        int cftS1 = (tid < 1023) ? curp[tid + 1] : 0;
        if (cftS >= PRE_NMS && cftS1 < PRE_NMS) { sSeg = tid; aboveC = cftS1; }
    }
    __syncthreads();
    if (tid < 64) nfine[tid] = (int)h[(sSeg << 6) | tid];
    __syncthreads();
    if (tid == 0) {
        int cum = aboveC;          // count of keys in buckets > current
        int t = sSeg << 6;
        for (int w = 63; w >= 0; --w) {
            int nc = cum + nfine[w];
            if (nc >= PRE_NMS) { t = (sSeg << 6) | w; break; }
            cum = nc;
        }
        thr = t;
        lcount = 0;
    }
    __syncthreads();

    // --- Phase B: compact keys with bucket >= thr into global ckeys ---
    ull* ck = ckeys + (size_t)img * SELN;
    {
        const ull* kb = keys + (size_t)img * NPROP;
        int th = thr;
        for (int i = tid; i < NPROP; i += 1024) {
            ull key = kb[i];
            if ((int)(key >> 48) >= th) {
                int p = atomicAdd(&lcount, 1);
                if (p < SELN) ck[p] = key;
            }
        }
    }
    __syncthreads();
    int M = lcount; if (M > SELN) M = SELN;
    if (tid == 0) mcount[img] = M;
    for (int e = M + tid; e < SELN; e += 1024) ck[e] = 0ull;
}

// ---------------------------------------------------------------------------
// Kernel 3: rank-by-count scatter (keys unique => rank is exact permutation).
// ---------------------------------------------------------------------------
__global__ __launch_bounds__(256) void rank_scatter(
        const ull* __restrict__ ckeys,
        const int* __restrict__ mcount,
        const float4* __restrict__ boxes4,
        float4* __restrict__ gboxes) {
    __shared__ ull lk[SELN];
    __shared__ int sM;
    int img = blockIdx.y, rb = blockIdx.x, tid = threadIdx.x;
    if (tid == 0) sM = mcount[img];
    __syncthreads();
    int M = sM;
    if (rb * 256 >= M) return;                 // whole block beyond last candidate
    int Ms = (M + 255) & ~255;                 // staged length (zero-padded)

    const ull* kb = ckeys + (size_t)img * SELN;
    for (int e = tid; e < Ms; e += 256) lk[e] = (e < M) ? kb[e] : 0ull;
    __syncthreads();

    int row = rb * 256 + tid;
    if (row >= M) return;
    ull my = lk[row];

    int rank = 0;
    #pragma unroll 8
    for (int e = 0; e < Ms; ++e) rank += (lk[e] > my) ? 1 : 0;

    if (rank < PRE_NMS) {
        uint32_t idx = 0xFFFFFFFFu - (uint32_t)(my & 0xFFFFFFFFull);
        gboxes[(size_t)img*PRE_NMS + rank] = boxes4[(size_t)img*NPROP + idx];
    }
}

// ---------------------------------------------------------------------------
// Kernel 4: suppression bit-matrix. Off-diagonal (cb>rb): row-major words
// (bit k = row i suppresses col cb*64+k). DIAGONAL (cb==rb): TRANSPOSED —
// thread tid writes COLUMN tid's word (bit k = row k suppresses col tid),
// enabling the scan's ballot-based within-window loop.
// ---------------------------------------------------------------------------
__global__ __launch_bounds__(64) void mask_kernel(const float4* __restrict__ gboxes,
                                                  ull* __restrict__ mask) {
    int rb = blockIdx.x, cb = blockIdx.y, b = blockIdx.z;
    if (cb < rb) return;
    __shared__ float cx1[64], cy1[64], cx2[64], cy2[64], car[64];
    int tid = threadIdx.x;

    int j0 = cb*64 + tid;
    float4 cbx = (j0 < PRE_NMS) ? gboxes[(size_t)b*PRE_NMS + j0]
                                : make_float4(0.f,0.f,0.f,0.f);
    cx1[tid]=cbx.x; cy1[tid]=cbx.y; cx2[tid]=cbx.z; cy2[tid]=cbx.w;
    car[tid]=(cbx.z-cbx.x+1.0f)*(cbx.w-cbx.y+1.0f);
    __syncthreads();

    int i = rb*64 + tid;
    if (i >= PRE_NMS) return;
    float4 rbx = gboxes[(size_t)b*PRE_NMS + i];
    float ix1=rbx.x, iy1=rbx.y, ix2=rbx.z, iy2=rbx.w;
    float iarea=(ix2-ix1+1.0f)*(iy2-iy1+1.0f);

    const bool diag = (rb == cb);
    ull bits = 0;
    #pragma unroll 16
    for (int k = 0; k < 64; ++k) {
        float xx1 = fmaxf(ix1, cx1[k]);
        float yy1 = fmaxf(iy1, cy1[k]);
        float xx2 = fminf(ix2, cx2[k]);
        float yy2 = fminf(iy2, cy2[k]);
        float ww = fmaxf(xx2 - xx1 + 1.0f, 0.0f);
        float hh = fmaxf(yy2 - yy1 + 1.0f, 0.0f);
        float inter = ww * hh;
        float iou = inter / (iarea + car[k] - inter);
        // diag (transposed): bit k = row k suppresses col tid => tid > k
        // off-diag: bit k = row i suppresses col j=cb*64+k (j>i automatic)
        bool cond = diag ? (tid > k) : ((cb*64 + k) < PRE_NMS);
        if (cond & (iou > NMS_T)) bits |= (1ull << k);
    }
    mask[(((size_t)b*MROWS + i) << 6) + cb] = bits;
}

// ---------------------------------------------------------------------------
// Kernel 5: greedy scan v4 (ballot-NMS). Window rows prefetched to LDS as
// before, but the per-kept critical chain is now pure registers:
// lane l holds column word tw; row c's within-window suppression word is
// reconstructed via __ballot((tw>>c)&1). Future-window supp reads deferred
// to window end (independent, pipelined, one waitcnt).
// ---------------------------------------------------------------------------
__global__ __launch_bounds__(64) void scan_kernel(const ull* __restrict__ mask,
                                                  const float4* __restrict__ gboxes,
                                                  float* __restrict__ out) {
    __shared__ ull buf[2][64][ROWSTRIDE];   // 64 KB double-buffered window rows
    __shared__ int keep_idx[POST_NMS];
    int b = blockIdx.x;
    int lane = threadIdx.x;
    const ull* mbase = mask + ((size_t)b * MROWS << 6);

    ull supp = 0;
    if (lane == NWORDS-1) supp = 0xFFFFFFFF00000000ull;  // candidates >= 4000
    if (lane >= NWORDS)   supp = ~0ull;
    int kept = 0;
    bool done = false;
    int cur = 0;

    // synchronous prefetch of window 0
    {
        const ulonglong2* src = (const ulonglong2*)mbase;
        ulonglong2* d2 = (ulonglong2*)buf[0];
        #pragma unroll
        for (int m = 0; m < 32; ++m) d2[lane + (m << 6)] = src[lane + (m << 6)];
        __syncthreads();
    }

    for (int wi = 0; wi < NWORDS && !done; ++wi) {
        // issue next-window loads into registers (overlaps with processing)
        ulonglong2 pf[32];
        bool havepf = (wi + 1 < NWORDS);
        if (havepf) {
            const ulonglong2* src =
                (const ulonglong2*)(mbase + (((size_t)(wi+1) << 6) << 6));
            #pragma unroll
            for (int m = 0; m < 32; ++m) pf[m] = src[lane + (m << 6)];
        }

        // lane l's transposed column word for this window (one LDS read)
        ull tw = buf[cur][lane][wi];
        ull avail = ~__shfl(supp, wi);       // uniform across lanes
        ull keptmask = 0;

        // fast loop: pure-register chain (ctz -> ballot -> andn2)
        while (avail) {
            int c = __builtin_ctzll(avail);
            if (lane == 0) keep_idx[kept] = (wi << 6) + c;
            ++kept;
            keptmask |= (1ull << c);
            if (kept >= POST_NMS) { done = true; break; }
            ull roww = __ballot((int)((tw >> c) & 1ull));  // row c window word
            avail &= ~roww;
            avail &= avail - 1;              // clear bit c
        }

        if (!done) {
            // deferred future-window suppression (independent LDS reads)
            ull km = keptmask;
            while (km) {
                int c = __builtin_ctzll(km); km &= km - 1;
                ull r = (lane > wi && lane < NWORDS) ? buf[cur][c][lane] : 0ull;
                supp |= r;
            }
            if (havepf) {
                ulonglong2* d2 = (ulonglong2*)buf[cur ^ 1];
                #pragma unroll
                for (int m = 0; m < 32; ++m) d2[lane + (m << 6)] = pf[m];
                __syncthreads();
                cur ^= 1;
            }
        }
    }
    __syncthreads();

    for (int r = lane; r < POST_NMS; r += 64) {
        float4 bx = (r < kept) ? gboxes[(size_t)b*PRE_NMS + keep_idx[r]]
                               : make_float4(0.f,0.f,0.f,0.f);
        float* o = out + (size_t)(b*POST_NMS + r)*5;
        o[0]=(float)b; o[1]=bx.x; o[2]=bx.y; o[3]=bx.z; o[4]=bx.w;
    }
}

// ---------------------------------------------------------------------------
extern "C" void kernel_launch(void* const* d_in, const int* in_sizes, int n_in,
                              void* d_out, int out_size, void* d_ws, size_t ws_size,
                              hipStream_t stream) {
    (void)n_in; (void)out_size; (void)ws_size;
    const float* scores  = (const float*)d_in[0];
    const float* deltas  = (const float*)d_in[1];
    const float* im_info = (const float*)d_in[2];
    const float* anchors = (const float*)d_in[3];
    float* out = (float*)d_out;

    const int B = in_sizes[0] / (2*NA*HH*WW);   // = 2

    // ws layout: boxes4 | gboxes | keys | ckeys | mask | hist | mcount
    float4* boxes4 = (float4*)d_ws;
    float4* gboxes = boxes4 + (size_t)B*NPROP;
    ull*    keys   = (ull*)(gboxes + (size_t)B*PRE_NMS);
    ull*    ckeys  = keys + (size_t)B*NPROP;
    ull*    mask   = ckeys + (size_t)B*SELN;
    uint32_t* hist = (uint32_t*)(mask + ((size_t)B*MROWS << 6));
    int*    mcount = (int*)(hist + (size_t)B*65536);

    hipMemsetAsync(hist, 0, (size_t)B*65536*sizeof(uint32_t), stream);
    decode_hist<<<(B*NPROP + 255)/256, 256, 0, stream>>>(scores, deltas, im_info,
                                                         anchors, keys, boxes4, hist, B);
    compact_kernel<<<B, 1024, 0, stream>>>(keys, hist, ckeys, mcount);
    dim3 rgrid(SELN/256, B);
    rank_scatter<<<rgrid, 256, 0, stream>>>(ckeys, mcount, boxes4, gboxes);
    dim3 mgrid(NWORDS, NWORDS, B);
    mask_kernel<<<mgrid, 64, 0, stream>>>(gboxes, mask);
    scan_kernel<<<B, 64, 0, stream>>>(mask, gboxes, out);
}